// Round 1
// baseline (117.890 us; speedup 1.0000x reference)
//
#include <hip/hip_runtime.h>

#define NB   16
#define INF  512
#define OUTF 512

// ---------------- Kernel 1: bucket rows by bank ----------------
// d_ws layout: counts[NB] ints, then lists[NB][nrows] ints.
__global__ void bucket_kernel(const int* __restrict__ sel, int* __restrict__ counts,
                              int* __restrict__ lists, int nrows) {
    int t = threadIdx.x;
    if (t < NB) counts[t] = 0;
    __syncthreads();
    for (int r = t; r < nrows; r += blockDim.x) {
        int b = sel[r];
        int pos = atomicAdd(&counts[b], 1);
        lists[b * nrows + pos] = r;
    }
}

// ---------------- Kernel 2: per-bank skinny GEMM ----------------
// Tile: MR=64 rows x NT=64 outs per block, K streamed in KT=32 chunks.
// 256 threads, each owns a 4x4 accumulator patch.
#define MR 64
#define NT 64
#define KT 32
#define PAD 36   // LDS row stride in floats: 16B-aligned (36%4==0), conflict-free xs reads

__global__ __launch_bounds__(256) void banked_gemm(
    const float* __restrict__ x, const float* __restrict__ W,
    const float* __restrict__ bias, const int* __restrict__ counts,
    const int* __restrict__ lists, float* __restrict__ out, int nrows_total) {
    int bank = blockIdx.z;
    int nrows = counts[bank];
    int row0 = blockIdx.y * MR;
    if (row0 >= nrows) return;

    __shared__ float xs[MR][PAD];
    __shared__ float ws[NT][PAD];
    __shared__ int ridx[MR];

    int t = threadIdx.x;
    if (t < MR) {
        int r = row0 + t;
        ridx[t] = (r < nrows) ? lists[bank * nrows_total + r] : -1;
    }
    __syncthreads();

    int tx = t & 15;   // out dimension (4 outs strided by 16)
    int ty = t >> 4;   // row dimension (4 rows strided by 16)
    int o_base = blockIdx.x * NT;
    const float* Wb = W + (size_t)bank * OUTF * INF;

    float acc[4][4] = {};

    // cooperative-load coordinates
    int lr = t >> 3;            // 0..31 (x rows; +32 for second half)
    int lk = (t & 7) * 4;       // x k-offset within tile
    int wo = t >> 2;            // 0..63 (W out row)
    int wk = (t & 3) * 8;       // W k-offset within tile (two float4s)

    int rg0 = ridx[lr];
    int rg1 = ridx[lr + 32];

    for (int kt = 0; kt < INF; kt += KT) {
        __syncthreads();
        float4 xv0 = make_float4(0.f, 0.f, 0.f, 0.f);
        float4 xv1 = xv0;
        if (rg0 >= 0) xv0 = *(const float4*)(x + (size_t)rg0 * INF + kt + lk);
        if (rg1 >= 0) xv1 = *(const float4*)(x + (size_t)rg1 * INF + kt + lk);
        *(float4*)&xs[lr][lk]      = xv0;
        *(float4*)&xs[lr + 32][lk] = xv1;
        const float* wp = Wb + (size_t)(o_base + wo) * INF + kt + wk;
        *(float4*)&ws[wo][wk]     = *(const float4*)wp;
        *(float4*)&ws[wo][wk + 4] = *(const float4*)(wp + 4);
        __syncthreads();

#pragma unroll
        for (int k = 0; k < KT; k += 4) {
            float4 a[4], w[4];
#pragma unroll
            for (int ri = 0; ri < 4; ++ri) a[ri] = *(float4*)&xs[ty + 16 * ri][k];
#pragma unroll
            for (int oi = 0; oi < 4; ++oi) w[oi] = *(float4*)&ws[tx + 16 * oi][k];
#pragma unroll
            for (int ri = 0; ri < 4; ++ri)
#pragma unroll
                for (int oi = 0; oi < 4; ++oi)
                    acc[ri][oi] += a[ri].x * w[oi].x + a[ri].y * w[oi].y
                                 + a[ri].z * w[oi].z + a[ri].w * w[oi].w;
        }
    }

#pragma unroll
    for (int oi = 0; oi < 4; ++oi) {
        float bv = bias[bank * OUTF + o_base + tx + 16 * oi];
#pragma unroll
        for (int ri = 0; ri < 4; ++ri) acc[ri][oi] += bv;
    }

#pragma unroll
    for (int ri = 0; ri < 4; ++ri) {
        int rl = ty + 16 * ri;
        if (row0 + rl < nrows) {
            int rg = ridx[rl];
            float* op = out + (size_t)rg * OUTF + o_base;
#pragma unroll
            for (int oi = 0; oi < 4; ++oi) op[tx + 16 * oi] = acc[ri][oi];
        }
    }
}

extern "C" void kernel_launch(void* const* d_in, const int* in_sizes, int n_in,
                              void* d_out, int out_size, void* d_ws, size_t ws_size,
                              hipStream_t stream) {
    const float* tensor = (const float*)d_in[0];   // (B,S,K,IN) fp32
    const int*   sel    = (const int*)d_in[1];     // (B,S,K) int32
    const float* weight = (const float*)d_in[2];   // (NB,OUT,IN) fp32
    const float* bias   = (const float*)d_in[3];   // (NB,OUT) fp32
    float* out = (float*)d_out;                    // (B,S,K,OUT) fp32

    int nrows = in_sizes[1];                       // B*S*K = 1024

    int* counts = (int*)d_ws;
    int* lists  = counts + NB;

    bucket_kernel<<<1, 1024, 0, stream>>>(sel, counts, lists, nrows);

    dim3 grid(OUTF / NT, (nrows + MR - 1) / MR, NB);
    banked_gemm<<<grid, 256, 0, stream>>>(tensor, weight, bias, counts, lists, out,
                                          nrows);
}